// Round 1
// baseline (715.554 us; speedup 1.0000x reference)
//
#include <hip/hip_runtime.h>
#include <hip/hip_bf16.h>
#include <math.h>

// Problem constants (fixed by reference)
#define C_B    8
#define C_HQ   32
#define C_TQ   128
#define C_D    128
#define C_HKV  8
#define C_MAXB 64
#define C_BS   128
#define C_NB   32
#define SCALE_F 0.08838834764831845f   // 128^-0.5

typedef __attribute__((ext_vector_type(8))) short bf16x8;  // 8 bf16 = 4 VGPRs
typedef __attribute__((ext_vector_type(4))) float f32x4;   // MFMA C/D
typedef __attribute__((ext_vector_type(4))) short s16x4;   // 4 bf16, 8B store

__device__ __forceinline__ unsigned f2bf(float f) {
    union { float f; unsigned u; } v; v.f = f;
    return (v.u + 0x7FFFu + ((v.u >> 16) & 1u)) >> 16;   // RNE fp32->bf16
}

// Swizzled byte offset inside a [rows][128] bf16 tile with 256B rows.
// 16B chunks permuted by row to break power-of-2 bank strides.
__device__ __forceinline__ int swz(int row, int e) {
    return row * 256 + ((((e >> 3) ^ row) & 15) << 4) + ((e & 7) << 1);
}

// 4x4 transpose across lane quads (lanes cl=lane&3 hold M[cl][0..3]; out M^T rows).
__device__ __forceinline__ void quad_transpose(int cl, float& v0, float& v1, float& v2, float& v3) {
    float t0 = (cl & 1) ? v0 : v1;  float r0 = __shfl_xor(t0, 1, 64);
    float t1 = (cl & 1) ? v2 : v3;  float r1 = __shfl_xor(t1, 1, 64);
    float u0 = (cl & 1) ? r0 : v0;
    float u1 = (cl & 1) ? v1 : r0;
    float u2 = (cl & 1) ? r1 : v2;
    float u3 = (cl & 1) ? v3 : r1;
    float s0 = (cl & 2) ? u0 : u2;  float q0 = __shfl_xor(s0, 2, 64);
    float s1 = (cl & 2) ? u1 : u3;  float q1 = __shfl_xor(s1, 2, 64);
    v0 = (cl & 2) ? q0 : u0;
    v1 = (cl & 2) ? q1 : u1;
    v2 = (cl & 2) ? u2 : q0;
    v3 = (cl & 2) ? u3 : q1;
}

__global__ __launch_bounds__(256, 1)
void MultiAttention_6339371729052_kernel(const float* __restrict__ q,
                                         const float* __restrict__ sk,
                                         const float* __restrict__ sv,
                                         const int*   __restrict__ btab,
                                         const int*   __restrict__ ctxl,
                                         float*       __restrict__ out)
{
    // 64KB LDS: K tile [128kv][128d] bf16 swizzled (overlaid by P after S-phase),
    //           V^T tile [128d][128kv] bf16 swizzled.
    __shared__ char lds[65536];
    char* ldsK = lds;
    char* ldsV = lds + 32768;

    // XCD-swizzled decode: the 4 rep-WGs of one (b,hkv) share bid%8 (same XCD).
    const int bid = blockIdx.x;
    const int g  = ((bid >> 5) << 3) | (bid & 7);   // 0..63 -> (b,hkv)
    const int rp = (bid >> 3) & 3;                  // rep 0..3
    const int b   = g >> 3;
    const int hkv = g & 7;
    const int hq  = hkv * 4 + rp;

    const int tid   = threadIdx.x;
    const int lane  = tid & 63;
    const int w     = tid >> 6;       // wave 0..3, owns t rows [w*32, w*32+32)
    const int lq    = lane & 15;      // MFMA m/n index
    const int q4    = lane >> 4;      // MFMA k-chunk / C-row quad
    const int lane3 = lane & 3;

    const int ctx  = ctxl[b];
    const int nblk = (ctx + C_BS - 1) / C_BS;

    // ---- Q fragments (pre-scaled), persistent in registers ----
    bf16x8 qf[2][4];
    {
        const float* qb = q + ((size_t)(b * C_HQ + hq) * C_TQ) * C_D;
        #pragma unroll
        for (int mi = 0; mi < 2; mi++)
        #pragma unroll
        for (int kc = 0; kc < 4; kc++) {
            const float* p = qb + (w * 32 + mi * 16 + lq) * C_D + kc * 32 + q4 * 8;
            float4 x = *(const float4*)p;
            float4 y = *(const float4*)(p + 4);
            bf16x8 f;
            f[0] = (short)f2bf(x.x * SCALE_F); f[1] = (short)f2bf(x.y * SCALE_F);
            f[2] = (short)f2bf(x.z * SCALE_F); f[3] = (short)f2bf(x.w * SCALE_F);
            f[4] = (short)f2bf(y.x * SCALE_F); f[5] = (short)f2bf(y.y * SCALE_F);
            f[6] = (short)f2bf(y.z * SCALE_F); f[7] = (short)f2bf(y.w * SCALE_F);
            qf[mi][kc] = f;
        }
    }

    bf16x8 onesf;
    #pragma unroll
    for (int i = 0; i < 8; i++) onesf[i] = (short)0x3F80;   // bf16 1.0

    f32x4 o[2][8];
    #pragma unroll
    for (int mi = 0; mi < 2; mi++)
        #pragma unroll
        for (int di = 0; di < 8; di++)
            o[mi][di] = (f32x4){0.f, 0.f, 0.f, 0.f};

    f32x4 lacc[2];
    lacc[0] = (f32x4){0.f, 0.f, 0.f, 0.f};
    lacc[1] = (f32x4){0.f, 0.f, 0.f, 0.f};

    float mrow[2][4];
    #pragma unroll
    for (int mi = 0; mi < 2; mi++)
        #pragma unroll
        for (int rr = 0; rr < 4; rr++) mrow[mi][rr] = -INFINITY;

    const size_t kvhead = (size_t)(b * C_HKV + hkv) * C_MAXB;

    for (int j = 0; j < nblk; j++) {
        const int pb = btab[b * C_NB + j];
        const float* kg = sk + (kvhead + pb) * (size_t)(C_BS * C_D);
        const float* vg = sv + (kvhead + pb) * (size_t)(C_BS * C_D);

        __syncthreads();   // prior iter's P/V reads complete before restaging

        // ---- stage K (natural bf16, swizzled) ----
        #pragma unroll 4
        for (int it = 0; it < 16; it++) {
            int c  = tid + it * 256;          // 0..4095 float4 chunks
            int kv = c >> 5;
            int d0 = (c & 31) << 2;
            float4 x = *(const float4*)(kg + kv * C_D + d0);
            s16x4 pk;
            pk[0] = (short)f2bf(x.x); pk[1] = (short)f2bf(x.y);
            pk[2] = (short)f2bf(x.z); pk[3] = (short)f2bf(x.w);
            *(s16x4*)(ldsK + swz(kv, d0)) = pk;
        }
        // ---- stage V transposed (V^T[d][kv]) via quad shuffle-transpose ----
        #pragma unroll 4
        for (int it = 0; it < 16; it++) {
            int kvb = w * 32 + (it >> 1) * 4;
            int d0  = (it & 1) * 64 + ((lane >> 2) & 15) * 4;
            float4 x = *(const float4*)(vg + (kvb + lane3) * C_D + d0);
            float a = x.x, bb = x.y, cc = x.z, dd = x.w;
            quad_transpose(lane3, a, bb, cc, dd);   // lane now: col d0+lane3, kv kvb..kvb+3
            s16x4 pk;
            pk[0] = (short)f2bf(a); pk[1] = (short)f2bf(bb);
            pk[2] = (short)f2bf(cc); pk[3] = (short)f2bf(dd);
            *(s16x4*)(ldsV + swz(d0 + lane3, kvb)) = pk;
        }

        __syncthreads();

        // ---- S = Q K^T (rows t, cols kv) ----
        f32x4 s[2][8];
        #pragma unroll
        for (int mi = 0; mi < 2; mi++)
            #pragma unroll
            for (int nt = 0; nt < 8; nt++) s[mi][nt] = (f32x4){0.f, 0.f, 0.f, 0.f};
        #pragma unroll
        for (int kc = 0; kc < 4; kc++) {
            #pragma unroll
            for (int nt = 0; nt < 8; nt++) {
                bf16x8 kf = *(const bf16x8*)(ldsK + swz(nt * 16 + lq, kc * 32 + q4 * 8));
                s[0][nt] = __builtin_amdgcn_mfma_f32_16x16x32_bf16(qf[0][kc], kf, s[0][nt], 0, 0, 0);
                s[1][nt] = __builtin_amdgcn_mfma_f32_16x16x32_bf16(qf[1][kc], kf, s[1][nt], 0, 0, 0);
            }
        }

        // ---- mask tail of last block (kv >= ctx) ----
        if (j == nblk - 1) {
            int lim = ctx - j * C_BS;   // 1..128
            #pragma unroll
            for (int nt = 0; nt < 8; nt++) {
                bool bad = (nt * 16 + lq) >= lim;
                #pragma unroll
                for (int mi = 0; mi < 2; mi++)
                    #pragma unroll
                    for (int rr = 0; rr < 4; rr++)
                        s[mi][nt][rr] = bad ? -1e30f : s[mi][nt][rr];
            }
        }

        // ---- online softmax (row = q4*4+rr within 16-tile; reduce over 16 lanes) ----
        float al[2][4];
        #pragma unroll
        for (int mi = 0; mi < 2; mi++) {
            #pragma unroll
            for (int rr = 0; rr < 4; rr++) {
                float mx = fmaxf(fmaxf(fmaxf(s[mi][0][rr], s[mi][1][rr]), fmaxf(s[mi][2][rr], s[mi][3][rr])),
                                 fmaxf(fmaxf(s[mi][4][rr], s[mi][5][rr]), fmaxf(s[mi][6][rr], s[mi][7][rr])));
                mx = fmaxf(mx, __shfl_xor(mx, 1, 64));
                mx = fmaxf(mx, __shfl_xor(mx, 2, 64));
                mx = fmaxf(mx, __shfl_xor(mx, 4, 64));
                mx = fmaxf(mx, __shfl_xor(mx, 8, 64));
                float mn = fmaxf(mrow[mi][rr], mx);
                al[mi][rr] = __expf(mrow[mi][rr] - mn);
                mrow[mi][rr] = mn;
                #pragma unroll
                for (int nt = 0; nt < 8; nt++)
                    s[mi][nt][rr] = __expf(s[mi][nt][rr] - mn);
            }
            #pragma unroll
            for (int di = 0; di < 8; di++)
                #pragma unroll
                for (int rr = 0; rr < 4; rr++)
                    o[mi][di][rr] *= al[mi][rr];
            #pragma unroll
            for (int rr = 0; rr < 4; rr++)
                lacc[mi][rr] *= al[mi][rr];
        }

        __syncthreads();   // all waves done reading K tile before P overlays it

        // ---- P (bf16) -> wave-private LDS region overlaying K ----
        char* ldsP = ldsK + w * 8192;     // [32 rows][128 kv], swizzled
        const int c4 = lq >> 2;
        #pragma unroll
        for (int mi = 0; mi < 2; mi++)
        #pragma unroll
        for (int nt = 0; nt < 8; nt++) {
            float a = s[mi][nt][0], bb = s[mi][nt][1], cc = s[mi][nt][2], dd = s[mi][nt][3];
            quad_transpose(lane3, a, bb, cc, dd);  // lane: row q4*4+lane3, cols c4*4..+3
            s16x4 pk;
            pk[0] = (short)f2bf(a); pk[1] = (short)f2bf(bb);
            pk[2] = (short)f2bf(cc); pk[3] = (short)f2bf(dd);
            *(s16x4*)(ldsP + swz(mi * 16 + q4 * 4 + lane3, nt * 16 + c4 * 4)) = pk;
        }

        // ---- O += P V ; denominator via MFMA against all-ones B fragment ----
        #pragma unroll
        for (int kc2 = 0; kc2 < 4; kc2++) {
            bf16x8 ap0 = *(const bf16x8*)(ldsP + swz(lq,      kc2 * 32 + q4 * 8));
            bf16x8 ap1 = *(const bf16x8*)(ldsP + swz(16 + lq, kc2 * 32 + q4 * 8));
            lacc[0] = __builtin_amdgcn_mfma_f32_16x16x32_bf16(ap0, onesf, lacc[0], 0, 0, 0);
            lacc[1] = __builtin_amdgcn_mfma_f32_16x16x32_bf16(ap1, onesf, lacc[1], 0, 0, 0);
            #pragma unroll
            for (int di = 0; di < 8; di++) {
                bf16x8 bv = *(const bf16x8*)(ldsV + swz(di * 16 + lq, kc2 * 32 + q4 * 8));
                o[0][di] = __builtin_amdgcn_mfma_f32_16x16x32_bf16(ap0, bv, o[0][di], 0, 0, 0);
                o[1][di] = __builtin_amdgcn_mfma_f32_16x16x32_bf16(ap1, bv, o[1][di], 0, 0, 0);
            }
        }
    }

    // ---- epilogue: divide by denominator, store fp32 ----
    float* ob = out + ((size_t)(b * C_HQ + hq) * C_TQ) * C_D;
    #pragma unroll
    for (int mi = 0; mi < 2; mi++)
    #pragma unroll
    for (int rr = 0; rr < 4; rr++) {
        float inv = 1.0f / fmaxf(lacc[mi][rr], 1e-9f);
        int t = w * 32 + mi * 16 + q4 * 4 + rr;
        #pragma unroll
        for (int di = 0; di < 8; di++)
            ob[(size_t)t * C_D + di * 16 + lq] = o[mi][di][rr] * inv;
    }
}

extern "C" void kernel_launch(void* const* d_in, const int* in_sizes, int n_in,
                              void* d_out, int out_size, void* d_ws, size_t ws_size,
                              hipStream_t stream) {
    const float* q  = (const float*)d_in[0];
    const float* sk = (const float*)d_in[1];
    const float* sv = (const float*)d_in[2];
    const int* btab = (const int*)d_in[3];
    const int* ctxl = (const int*)d_in[4];
    float* out = (float*)d_out;
    (void)in_sizes; (void)n_in; (void)out_size; (void)d_ws; (void)ws_size;

    hipLaunchKernelGGL(MultiAttention_6339371729052_kernel,
                       dim3(C_B * C_HKV * 4), dim3(256), 0, stream,
                       q, sk, sv, btab, ctxl, out);
}

// Round 2
// 627.122 us; speedup vs baseline: 1.1410x; 1.1410x over previous
//
#include <hip/hip_runtime.h>
#include <hip/hip_bf16.h>
#include <math.h>

// Problem constants (fixed by reference)
#define C_B    8
#define C_HQ   32
#define C_TQ   128
#define C_D    128
#define C_HKV  8
#define C_MAXB 64
#define C_BS   128
#define C_NB   32
#define SCALE_F 0.08838834764831845f   // 128^-0.5

typedef __attribute__((ext_vector_type(8))) short bf16x8;  // 8 bf16 = 4 VGPRs
typedef __attribute__((ext_vector_type(4))) float f32x4;   // MFMA C/D
typedef __attribute__((ext_vector_type(4))) short s16x4;   // 4 bf16, 8B store

__device__ __forceinline__ unsigned f2bf(float f) {
    union { float f; unsigned u; } v; v.f = f;
    return (v.u + 0x7FFFu + ((v.u >> 16) & 1u)) >> 16;   // RNE fp32->bf16
}

// Swizzled byte offset inside a [rows][128] bf16 tile with 256B rows.
__device__ __forceinline__ int swz(int row, int e) {
    return row * 256 + ((((e >> 3) ^ row) & 15) << 4) + ((e & 7) << 1);
}

// 4x4 transpose across lane quads.
__device__ __forceinline__ void quad_transpose(int cl, float& v0, float& v1, float& v2, float& v3) {
    float t0 = (cl & 1) ? v0 : v1;  float r0 = __shfl_xor(t0, 1, 64);
    float t1 = (cl & 1) ? v2 : v3;  float r1 = __shfl_xor(t1, 1, 64);
    float u0 = (cl & 1) ? r0 : v0;
    float u1 = (cl & 1) ? v1 : r0;
    float u2 = (cl & 1) ? r1 : v2;
    float u3 = (cl & 1) ? v3 : r1;
    float s0 = (cl & 2) ? u0 : u2;  float q0 = __shfl_xor(s0, 2, 64);
    float s1 = (cl & 2) ? u1 : u3;  float q1 = __shfl_xor(s1, 2, 64);
    v0 = (cl & 2) ? q0 : u0;
    v1 = (cl & 2) ? q1 : u1;
    v2 = (cl & 2) ? u2 : q0;
    v3 = (cl & 2) ? u3 : q1;
}

// Main flash kernel with split-KV. S (power of 2) splits of the KV stream.
// S==1: writes normalized fp32 directly to out. S>1: writes per-split
// normalized bf16 O + (m,l) stats to workspace; combine kernel merges.
__global__ __launch_bounds__(256, 2)
void MultiAttention_6339371729052_kernel(const float* __restrict__ q,
                                         const float* __restrict__ sk,
                                         const float* __restrict__ sv,
                                         const int*   __restrict__ btab,
                                         const int*   __restrict__ ctxl,
                                         float*       __restrict__ out,
                                         unsigned short* __restrict__ Op,
                                         float2*      __restrict__ st,
                                         int S, int lgS)
{
    __shared__ char lds[65536];
    char* ldsK = lds;
    char* ldsV = lds + 32768;

    // XCD-aware decode: the 4 rep-WGs of one (b,hkv,split) land on one XCD
    // (they read the identical KV stream -> L2 dedup).
    const int bid = blockIdx.x;
    const int xcd = bid & 7;
    const int r   = bid >> 3;
    const int grp_in = r & (S * 8 - 1);
    const int rp  = r >> (lgS + 3);                 // rep 0..3
    const int grp = xcd + 8 * grp_in;               // 0..64*S-1
    const int bhkv  = grp >> lgS;                   // 0..63
    const int s_idx = grp & (S - 1);                // split id
    const int b   = bhkv >> 3;
    const int hkv = bhkv & 7;
    const int hq  = hkv * 4 + rp;

    const int tid   = threadIdx.x;
    const int lane  = tid & 63;
    const int w     = tid >> 6;       // wave 0..3, owns t rows [w*32, w*32+32)
    const int lq    = lane & 15;      // MFMA m/n index
    const int q4    = lane >> 4;      // MFMA k-chunk / C-row quad
    const int lane3 = lane & 3;

    const int ctx  = ctxl[b];
    const int nblk = (ctx + C_BS - 1) / C_BS;
    const int bps  = C_NB >> lgS;                   // blocks per split
    const int j0   = s_idx * bps;
    const int j1   = min(nblk, j0 + bps);

    const size_t rowbase = (size_t)(b * C_HQ + hq) * C_TQ;   // (b,hq) row offset

    if (S > 1 && j0 >= j1) {
        // Empty split: publish l=0 stats so combine skips us.
        if (tid < C_TQ)
            st[(rowbase + tid) * S + s_idx] = make_float2(-1e30f, 0.0f);
        return;
    }

    // ---- Q fragments (pre-scaled), persistent in registers ----
    bf16x8 qf[2][4];
    {
        const float* qb = q + rowbase * C_D;
        #pragma unroll
        for (int mi = 0; mi < 2; mi++)
        #pragma unroll
        for (int kc = 0; kc < 4; kc++) {
            const float* p = qb + (w * 32 + mi * 16 + lq) * C_D + kc * 32 + q4 * 8;
            float4 x = *(const float4*)p;
            float4 y = *(const float4*)(p + 4);
            bf16x8 f;
            f[0] = (short)f2bf(x.x * SCALE_F); f[1] = (short)f2bf(x.y * SCALE_F);
            f[2] = (short)f2bf(x.z * SCALE_F); f[3] = (short)f2bf(x.w * SCALE_F);
            f[4] = (short)f2bf(y.x * SCALE_F); f[5] = (short)f2bf(y.y * SCALE_F);
            f[6] = (short)f2bf(y.z * SCALE_F); f[7] = (short)f2bf(y.w * SCALE_F);
            qf[mi][kc] = f;
        }
    }

    bf16x8 onesf;
    #pragma unroll
    for (int i = 0; i < 8; i++) onesf[i] = (short)0x3F80;   // bf16 1.0

    f32x4 o[2][8];
    #pragma unroll
    for (int mi = 0; mi < 2; mi++)
        #pragma unroll
        for (int di = 0; di < 8; di++)
            o[mi][di] = (f32x4){0.f, 0.f, 0.f, 0.f};

    f32x4 lacc[2];
    lacc[0] = (f32x4){0.f, 0.f, 0.f, 0.f};
    lacc[1] = (f32x4){0.f, 0.f, 0.f, 0.f};

    float mrow[2][4];
    #pragma unroll
    for (int mi = 0; mi < 2; mi++)
        #pragma unroll
        for (int rr = 0; rr < 4; rr++) mrow[mi][rr] = -INFINITY;

    const size_t kvhead = (size_t)(b * C_HKV + hkv) * C_MAXB;

    for (int j = j0; j < j1; j++) {
        const int pb = btab[b * C_NB + j];
        const float* kg = sk + (kvhead + pb) * (size_t)(C_BS * C_D);
        const float* vg = sv + (kvhead + pb) * (size_t)(C_BS * C_D);

        __syncthreads();   // prior iter's P/V reads complete before restaging

        // ---- stage K (natural bf16, swizzled) ----
        #pragma unroll 4
        for (int it = 0; it < 16; it++) {
            int c  = tid + it * 256;          // 0..4095 float4 chunks
            int kv = c >> 5;
            int d0 = (c & 31) << 2;
            float4 x = *(const float4*)(kg + kv * C_D + d0);
            s16x4 pk;
            pk[0] = (short)f2bf(x.x); pk[1] = (short)f2bf(x.y);
            pk[2] = (short)f2bf(x.z); pk[3] = (short)f2bf(x.w);
            *(s16x4*)(ldsK + swz(kv, d0)) = pk;
        }
        // ---- stage V transposed (V^T[d][kv]) via quad shuffle-transpose ----
        #pragma unroll 4
        for (int it = 0; it < 16; it++) {
            int kvb = w * 32 + (it >> 1) * 4;
            int d0  = (it & 1) * 64 + ((lane >> 2) & 15) * 4;
            float4 x = *(const float4*)(vg + (kvb + lane3) * C_D + d0);
            float a = x.x, bb = x.y, cc = x.z, dd = x.w;
            quad_transpose(lane3, a, bb, cc, dd);
            s16x4 pk;
            pk[0] = (short)f2bf(a); pk[1] = (short)f2bf(bb);
            pk[2] = (short)f2bf(cc); pk[3] = (short)f2bf(dd);
            *(s16x4*)(ldsV + swz(d0 + lane3, kvb)) = pk;
        }

        __syncthreads();

        // ---- S = Q K^T ----
        f32x4 s[2][8];
        #pragma unroll
        for (int mi = 0; mi < 2; mi++)
            #pragma unroll
            for (int nt = 0; nt < 8; nt++) s[mi][nt] = (f32x4){0.f, 0.f, 0.f, 0.f};
        #pragma unroll
        for (int kc = 0; kc < 4; kc++) {
            #pragma unroll
            for (int nt = 0; nt < 8; nt++) {
                bf16x8 kf = *(const bf16x8*)(ldsK + swz(nt * 16 + lq, kc * 32 + q4 * 8));
                s[0][nt] = __builtin_amdgcn_mfma_f32_16x16x32_bf16(qf[0][kc], kf, s[0][nt], 0, 0, 0);
                s[1][nt] = __builtin_amdgcn_mfma_f32_16x16x32_bf16(qf[1][kc], kf, s[1][nt], 0, 0, 0);
            }
        }

        // ---- mask tail of last block (kv >= ctx) ----
        if (j == nblk - 1) {
            int lim = ctx - j * C_BS;   // 1..128
            #pragma unroll
            for (int nt = 0; nt < 8; nt++) {
                bool bad = (nt * 16 + lq) >= lim;
                #pragma unroll
                for (int mi = 0; mi < 2; mi++)
                    #pragma unroll
                    for (int rr = 0; rr < 4; rr++)
                        s[mi][nt][rr] = bad ? -1e30f : s[mi][nt][rr];
            }
        }

        // ---- online softmax ----
        float al[2][4];
        #pragma unroll
        for (int mi = 0; mi < 2; mi++) {
            #pragma unroll
            for (int rr = 0; rr < 4; rr++) {
                float mx = fmaxf(fmaxf(fmaxf(s[mi][0][rr], s[mi][1][rr]), fmaxf(s[mi][2][rr], s[mi][3][rr])),
                                 fmaxf(fmaxf(s[mi][4][rr], s[mi][5][rr]), fmaxf(s[mi][6][rr], s[mi][7][rr])));
                mx = fmaxf(mx, __shfl_xor(mx, 1, 64));
                mx = fmaxf(mx, __shfl_xor(mx, 2, 64));
                mx = fmaxf(mx, __shfl_xor(mx, 4, 64));
                mx = fmaxf(mx, __shfl_xor(mx, 8, 64));
                float mn = fmaxf(mrow[mi][rr], mx);
                al[mi][rr] = __expf(mrow[mi][rr] - mn);
                mrow[mi][rr] = mn;
                #pragma unroll
                for (int nt = 0; nt < 8; nt++)
                    s[mi][nt][rr] = __expf(s[mi][nt][rr] - mn);
            }
            #pragma unroll
            for (int di = 0; di < 8; di++)
                #pragma unroll
                for (int rr = 0; rr < 4; rr++)
                    o[mi][di][rr] *= al[mi][rr];
            #pragma unroll
            for (int rr = 0; rr < 4; rr++)
                lacc[mi][rr] *= al[mi][rr];
        }

        __syncthreads();   // all waves done reading K tile before P overlays it

        // ---- P (bf16) -> wave-private LDS region overlaying K ----
        char* ldsP = ldsK + w * 8192;     // [32 rows][128 kv], swizzled
        const int c4 = lq >> 2;
        #pragma unroll
        for (int mi = 0; mi < 2; mi++)
        #pragma unroll
        for (int nt = 0; nt < 8; nt++) {
            float a = s[mi][nt][0], bb = s[mi][nt][1], cc = s[mi][nt][2], dd = s[mi][nt][3];
            quad_transpose(lane3, a, bb, cc, dd);
            s16x4 pk;
            pk[0] = (short)f2bf(a); pk[1] = (short)f2bf(bb);
            pk[2] = (short)f2bf(cc); pk[3] = (short)f2bf(dd);
            *(s16x4*)(ldsP + swz(mi * 16 + q4 * 4 + lane3, nt * 16 + c4 * 4)) = pk;
        }

        // ---- O += P V ; denominator via MFMA against all-ones B fragment ----
        #pragma unroll
        for (int kc2 = 0; kc2 < 4; kc2++) {
            bf16x8 ap0 = *(const bf16x8*)(ldsP + swz(lq,      kc2 * 32 + q4 * 8));
            bf16x8 ap1 = *(const bf16x8*)(ldsP + swz(16 + lq, kc2 * 32 + q4 * 8));
            lacc[0] = __builtin_amdgcn_mfma_f32_16x16x32_bf16(ap0, onesf, lacc[0], 0, 0, 0);
            lacc[1] = __builtin_amdgcn_mfma_f32_16x16x32_bf16(ap1, onesf, lacc[1], 0, 0, 0);
            #pragma unroll
            for (int di = 0; di < 8; di++) {
                bf16x8 bv = *(const bf16x8*)(ldsV + swz(di * 16 + lq, kc2 * 32 + q4 * 8));
                o[0][di] = __builtin_amdgcn_mfma_f32_16x16x32_bf16(ap0, bv, o[0][di], 0, 0, 0);
                o[1][di] = __builtin_amdgcn_mfma_f32_16x16x32_bf16(ap1, bv, o[1][di], 0, 0, 0);
            }
        }
    }

    // ---- epilogue ----
    if (S == 1) {
        float* ob = out + rowbase * C_D;
        #pragma unroll
        for (int mi = 0; mi < 2; mi++)
        #pragma unroll
        for (int rr = 0; rr < 4; rr++) {
            float inv = 1.0f / fmaxf(lacc[mi][rr], 1e-9f);
            int t = w * 32 + mi * 16 + q4 * 4 + rr;
            #pragma unroll
            for (int di = 0; di < 8; di++)
                ob[(size_t)t * C_D + di * 16 + lq] = o[mi][di][rr] * inv;
        }
    } else {
        // Per-split normalized O (bf16) + (m,l) stats.
        #pragma unroll
        for (int mi = 0; mi < 2; mi++)
        #pragma unroll
        for (int rr = 0; rr < 4; rr++) {
            float l   = lacc[mi][rr];
            float inv = (l > 0.f) ? 1.0f / l : 0.0f;
            int t = w * 32 + mi * 16 + q4 * 4 + rr;
            unsigned short* ob = Op + ((rowbase + t) * S + s_idx) * C_D;
            #pragma unroll
            for (int di = 0; di < 8; di++)
                ob[di * 16 + lq] = (unsigned short)f2bf(o[mi][di][rr] * inv);
            if (lq == 0)
                st[(rowbase + t) * S + s_idx] = make_float2(mrow[mi][rr], l);
        }
    }
}

// Merge per-split partials: out = sum_s l_s exp(m_s - m*) O_s / sum_s l_s exp(m_s - m*)
__global__ __launch_bounds__(256, 4)
void combine_kernel(const unsigned short* __restrict__ Op,
                    const float2* __restrict__ st,
                    float* __restrict__ out, int S)
{
    const int wave = threadIdx.x >> 6;
    const int lane = threadIdx.x & 63;
    const size_t row = (size_t)blockIdx.x * 4 + wave;       // 0..B*HQ*TQ-1

    const float2* sr = st + row * S;
    float mstar = -INFINITY;
    for (int s = 0; s < S; s++) {
        float2 v = sr[s];
        if (v.y > 0.f) mstar = fmaxf(mstar, v.x);
    }
    float acc0 = 0.f, acc1 = 0.f, wsum = 0.f;
    for (int s = 0; s < S; s++) {
        float2 v = sr[s];
        float wgt = (v.y > 0.f) ? v.y * __expf(v.x - mstar) : 0.f;
        wsum += wgt;
        unsigned u = *(const unsigned*)(Op + (row * S + s) * C_D + lane * 2);
        float o0 = __uint_as_float((u & 0xFFFFu) << 16);
        float o1 = __uint_as_float((u >> 16) << 16);
        acc0 += wgt * o0;
        acc1 += wgt * o1;
    }
    float inv = (wsum > 0.f) ? 1.0f / wsum : 0.f;
    out[row * C_D + lane * 2]     = acc0 * inv;
    out[row * C_D + lane * 2 + 1] = acc1 * inv;
}

extern "C" void kernel_launch(void* const* d_in, const int* in_sizes, int n_in,
                              void* d_out, int out_size, void* d_ws, size_t ws_size,
                              hipStream_t stream) {
    const float* q  = (const float*)d_in[0];
    const float* sk = (const float*)d_in[1];
    const float* sv = (const float*)d_in[2];
    const int* btab = (const int*)d_in[3];
    const int* ctxl = (const int*)d_in[4];
    float* out = (float*)d_out;
    (void)in_sizes; (void)n_in; (void)out_size;

    const size_t rows   = (size_t)C_B * C_HQ * C_TQ;          // 32768
    const size_t perSO  = rows * C_D * 2;                     // bf16 partial O per split
    const size_t perSst = rows * sizeof(float2);              // stats per split

    int S = 1, lgS = 0;
    if (ws_size >= 4 * (perSO + perSst))      { S = 4; lgS = 2; }
    else if (ws_size >= 2 * (perSO + perSst)) { S = 2; lgS = 1; }

    unsigned short* Op = (unsigned short*)d_ws;
    float2* st = (float2*)((char*)d_ws + (size_t)S * perSO);

    hipLaunchKernelGGL(MultiAttention_6339371729052_kernel,
                       dim3(C_B * C_HKV * 4 * S), dim3(256), 0, stream,
                       q, sk, sv, btab, ctxl, out, Op, st, S, lgS);
    if (S > 1) {
        hipLaunchKernelGGL(combine_kernel,
                           dim3(rows / 4), dim3(256), 0, stream,
                           Op, st, out, S);
    }
}